// Round 1
// baseline (23259.450 us; speedup 1.0000x reference)
//
#include <hip/hip_runtime.h>
#include <hip/hip_cooperative_groups.h>

namespace cg = cooperative_groups;

typedef unsigned short ushort_t;
typedef unsigned int uint32;

typedef short bf16x8 __attribute__((ext_vector_type(8)));
typedef float f32x4 __attribute__((ext_vector_type(4)));

#define HH 1024
#define BB 32
#define U1 257
#define VV 10001
#define MM (U1*BB)   /* 8224 */
#define KK 1024

__device__ __forceinline__ ushort_t f2bf(float f){
    union { float f; uint32 i; } c; c.f = f;
    uint32 u = c.i;
    uint32 r = (u + 0x7fffu + ((u >> 16) & 1u)) >> 16;  // RNE
    return (ushort_t)r;
}

__global__ __launch_bounds__(256) void k_cast(const float* __restrict__ src,
                                              ushort_t* __restrict__ dst, int n){
    int i = blockIdx.x*256 + threadIdx.x;
    int stride = gridDim.x*256;
    for (; i < n; i += stride) dst[i] = f2bf(src[i]);
}

// x0[(t*32+b)*H + k] = bf16(embed[token(t,b)*H + k]); token = start for t=0 else y[b][t-1]
__global__ __launch_bounds__(256) void k_embed(const int* __restrict__ y,
                                               const float* __restrict__ embed,
                                               ushort_t* __restrict__ x0){
    int i = blockIdx.x*256 + threadIdx.x;
    int stride = gridDim.x*256;
    const int n = MM*HH;
    for (; i < n; i += stride){
        int m = i >> 10, k = i & 1023;
        int t = m >> 5, b = m & 31;
        int tok = (t == 0) ? (VV-1) : y[b*256 + (t-1)];
        x0[i] = f2bf(embed[(size_t)tok*HH + k]);
    }
}

// ---------------------------------------------------------------------------
// Persistent GRU layer: all 257 steps in ONE cooperative kernel.
// 256 WGs x 256 threads, 1 WG/CU. WG wg owns out_j in [wg*4, wg*4+4).
// Its 12 Whh rows (r/z/n gates) are staged ONCE into LDS as fp32 (48 KB).
// Thread = (j_local = (tid>>5)&3, b = tid&31, khalf = tid>>7): each computes
// half-K partial dots; halves combined via 1.5 KB LDS; grid.sync() per step.
// h state lives in global ping-pong buffers with interleaved layout
//   hidx(k,b) = (k>>2)*128 + b*4 + (k&3)
// so a thread's float4 load of h[k..k+3] is perfectly coalesced across b.
// ---------------------------------------------------------------------------
__global__ __launch_bounds__(256) void k_gru_layer(
    const float* __restrict__ Whh,   // [3072][1024] fp32 (layer base)
    const float* __restrict__ bhh,   // [3072]  (layer base)
    const float* __restrict__ gi,    // [257][32][3072] fp32 (includes bih)
    const float* __restrict__ hinit, // [1024] init_state row for this layer
    float* __restrict__ hA,          // interleaved fp32, 32768 floats (ping)
    float* __restrict__ hB,          // (pong)
    ushort_t* __restrict__ hout)     // [257][32][1024] bf16
{
    cg::grid_group grid = cg::this_grid();
    __shared__ float wlds[12*1024];   // 48 KB fp32 weights
    __shared__ float part[3][128];    // khalf=1 partial sums

    const int tid = threadIdx.x;
    const int b  = tid & 31;
    const int jl = (tid >> 5) & 3;
    const int kh = tid >> 7;              // 0: waves 0-1, 1: waves 2-3
    const int j0 = blockIdx.x * 4;
    const int j  = j0 + jl;

    // stage 12 fp32 weight rows: LDS row (g*4+jl) <- Whh[g*1024 + j0+jl]
    for (int i = tid; i < 3072; i += 256){        // 3072 float4s
        int row = i >> 8;                         // 0..11
        int e   = (i & 255) << 2;                 // float offset in row
        int g = row >> 2, jj = row & 3;
        *(float4*)&wlds[row*1024 + e] =
            *(const float4*)(Whh + ((size_t)(g*1024 + j0 + jj))*1024 + e);
    }

    // init h into ping buffer (kh0 threads cover 4j x 32b)
    if (kh == 0)
        hA[((j >> 2)*128) + b*4 + (j & 3)] = hinit[j];

    float bhr = 0.f, bhz = 0.f, bhn = 0.f;
    if (kh == 0){ bhr = bhh[j]; bhz = bhh[HH + j]; bhn = bhh[2*HH + j]; }

    const float* wr = wlds + (0 + jl)*1024;
    const float* wz = wlds + (4 + jl)*1024;
    const float* wn = wlds + (8 + jl)*1024;
    const int hoff = kh*16384 + b*4;   // ((kh*512)>>2)*128 + b*4
    const int kb = kh << 9;

    __syncthreads();   // wlds ready
    grid.sync();       // h init visible grid-wide

    for (int t = 0; t < U1; t++){
        const float* __restrict__ hp  = (t & 1) ? hB : hA;
        float*       __restrict__ hn_ = (t & 1) ? hA : hB;

        // issue long-latency scalar loads early (wave-uniform guard: waves 0-1)
        float gir = 0.f, giz = 0.f, gin = 0.f, hj = 0.f;
        if (kh == 0){
            const float* girow = gi + ((size_t)t*BB + b)*3072;
            gir = girow[j]; giz = girow[HH + j]; gin = girow[2*HH + j];
            hj  = hp[((j >> 2)*128) + b*4 + (j & 3)];
        }

        float ar = 0.f, az = 0.f, an = 0.f;
        const float* hpk = hp + hoff;
        #pragma unroll 4
        for (int i = 0; i < 128; i++){
            const float4 hv = *(const float4*)(hpk + i*128);
            const int k = kb + (i << 2);
            ar += wr[k]*hv.x + wr[k+1]*hv.y + wr[k+2]*hv.z + wr[k+3]*hv.w;
            az += wz[k]*hv.x + wz[k+1]*hv.y + wz[k+2]*hv.z + wz[k+3]*hv.w;
            an += wn[k]*hv.x + wn[k+1]*hv.y + wn[k+2]*hv.z + wn[k+3]*hv.w;
        }

        if (kh == 1){
            int c = tid - 128;
            part[0][c] = ar; part[1][c] = az; part[2][c] = an;
        }
        __syncthreads();
        if (kh == 0){
            ar += part[0][tid]; az += part[1][tid]; an += part[2][tid];
            float r  = 1.f/(1.f + __expf(-(gir + ar + bhr)));
            float z  = 1.f/(1.f + __expf(-(giz + az + bhz)));
            float nn = tanhf(gin + r*(an + bhn));
            float h  = (1.f - z)*nn + z*hj;
            hn_[((j >> 2)*128) + b*4 + (j & 3)] = h;
            hout[(size_t)t*(BB*HH) + b*HH + j] = f2bf(h);
        }
        grid.sync();   // h(t) visible everywhere before step t+1
    }
}

// C = A @ B^T + bias.  A: [M][1024] bf16. B: [N][1024] row-major, bf16 (BFP32=0)
// or fp32 (BFP32=1, converted in-register). mode 0: C[row*N+col].
// mode 1: row=(t*32+b) -> C[b*(257*V) + t*V + col] (projection layout).
template<int BFP32>
__global__ __launch_bounds__(256) void k_gemm_bt(
    const ushort_t* __restrict__ A, int M,
    const void* __restrict__ Bv, int N,
    const float* __restrict__ bias,
    float* __restrict__ C, int mode)
{
    int wave = threadIdx.x >> 6;
    int lane = threadIdx.x & 63;
    int quad = lane >> 4;
    int l16  = lane & 15;
    int m0 = blockIdx.y*128 + (wave >> 1)*64;
    int n0 = blockIdx.x*128 + (wave & 1)*64;

    const ushort_t* pA[4];
    const ushort_t* pBh[4];
    const float*    pBf[4];
    #pragma unroll
    for (int i = 0; i < 4; i++){
        int r = m0 + i*16 + l16; if (r > M-1) r = M-1;
        pA[i] = A + (size_t)r*KK + quad*8;
        int c = n0 + i*16 + l16; if (c > N-1) c = N-1;
        if (BFP32) pBf[i] = (const float*)Bv + (size_t)c*KK + quad*8;
        else       pBh[i] = (const ushort_t*)Bv + (size_t)c*KK + quad*8;
    }
    f32x4 acc[4][4];
    #pragma unroll
    for (int i = 0; i < 4; i++)
        #pragma unroll
        for (int j = 0; j < 4; j++){
            f32x4 z4 = {0.f, 0.f, 0.f, 0.f};
            acc[i][j] = z4;
        }

    for (int kc = 0; kc < KK; kc += 32){
        bf16x8 av[4], bv[4];
        #pragma unroll
        for (int i = 0; i < 4; i++) av[i] = *(const bf16x8*)(pA[i] + kc);
        #pragma unroll
        for (int j = 0; j < 4; j++){
            if (BFP32){
                float4 f0 = *(const float4*)(pBf[j] + kc);
                float4 f1 = *(const float4*)(pBf[j] + kc + 4);
                bf16x8 t;
                t[0]=(short)f2bf(f0.x); t[1]=(short)f2bf(f0.y);
                t[2]=(short)f2bf(f0.z); t[3]=(short)f2bf(f0.w);
                t[4]=(short)f2bf(f1.x); t[5]=(short)f2bf(f1.y);
                t[6]=(short)f2bf(f1.z); t[7]=(short)f2bf(f1.w);
                bv[j] = t;
            } else {
                bv[j] = *(const bf16x8*)(pBh[j] + kc);
            }
        }
        #pragma unroll
        for (int i = 0; i < 4; i++)
            #pragma unroll
            for (int j = 0; j < 4; j++)
                acc[i][j] = __builtin_amdgcn_mfma_f32_16x16x32_bf16(av[i], bv[j], acc[i][j], 0, 0, 0);
    }

    #pragma unroll
    for (int i = 0; i < 4; i++){
        int rbase = m0 + i*16 + quad*4;
        #pragma unroll
        for (int j = 0; j < 4; j++){
            int col = n0 + j*16 + l16;
            if (col >= N) continue;
            float bvv = bias[col];
            #pragma unroll
            for (int rr = 0; rr < 4; rr++){
                int row = rbase + rr;
                if (row >= M) continue;
                float v = acc[i][j][rr] + bvv;
                if (mode == 0) C[(size_t)row*N + col] = v;
                else {
                    int t = row >> 5, b = row & 31;
                    C[(size_t)b*((size_t)U1*VV) + (size_t)t*VV + col] = v;
                }
            }
        }
    }
}

extern "C" void kernel_launch(void* const* d_in, const int* in_sizes, int n_in,
                              void* d_out, int out_size, void* d_ws, size_t ws_size,
                              hipStream_t stream)
{
    const int*   y          = (const int*)  d_in[0];
    const float* embed      = (const float*)d_in[2];
    const float* init_state = (const float*)d_in[3];
    const float* Wih        = (const float*)d_in[4];
    const float* Whh        = (const float*)d_in[5];
    const float* bih        = (const float*)d_in[6];
    const float* bhh        = (const float*)d_in[7];
    const float* Wout       = (const float*)d_in[8];
    const float* bout       = (const float*)d_in[9];
    float* out = (float*)d_out;

    // ---- d_out as scratch (all regions dead before the projection) ----
    float* gi0 = out;                              // 101.1 MB (MM*3072 fp32)
    float* gi1 = out + (size_t)MM*3072;            // 101.1 MB
    char*  r2  = (char*)(out + (size_t)2*MM*3072); // spare
    ushort_t* x0   = (ushort_t*)r2;                      // 16.84 MB
    ushort_t* h0   = (ushort_t*)(r2 + (size_t)MM*HH*2);  // 16.84 MB
    ushort_t* WihB = (ushort_t*)(r2 + (size_t)2*MM*HH*2);// 12.58 MB

    // ---- d_ws: buffers that must survive the projection ----
    char* w = (char*)d_ws;
    ushort_t* h1  = (ushort_t*)w; w += (size_t)MM*HH*2;   // 16.84 MB
    float*    hTa = (float*)w;    w += (size_t)32768*4;
    float*    hTb = (float*)w;    w += (size_t)32768*4;
    size_t used_b = (size_t)(w - (char*)d_ws);
    size_t need_a = used_b + (size_t)VV*1024*2;           // +20.48 MB WoutB
    int planA = (ws_size >= need_a) ? 1 : 0;
    ushort_t* WoutB = (ushort_t*)w;

    k_cast<<<2048, 256, 0, stream>>>(Wih,  WihB,  2*3072*1024);
    if (planA)
        k_cast<<<2048, 256, 0, stream>>>(Wout, WoutB, VV*1024);
    k_embed<<<4096, 256, 0, stream>>>(y, embed, x0);

    // layer 0: batched gi GEMM, then one persistent cooperative recurrence
    k_gemm_bt<0><<<dim3(24, 65), 256, 0, stream>>>(x0, MM, WihB, 3072, bih, gi0, 0);
    {
        const float* whh_l = Whh;                 // fp32 weights, staged in-kernel
        const float* bhh_l = bhh;
        const float* gi_l  = gi0;
        const float* hi_l  = init_state;
        ushort_t*    ho_l  = h0;
        void* args[] = {(void*)&whh_l, (void*)&bhh_l, (void*)&gi_l, (void*)&hi_l,
                        (void*)&hTa, (void*)&hTb, (void*)&ho_l};
        hipLaunchCooperativeKernel((const void*)k_gru_layer, dim3(256), dim3(256),
                                   args, 0, stream);
    }

    // layer 1
    k_gemm_bt<0><<<dim3(24, 65), 256, 0, stream>>>(h0, MM, WihB + (size_t)3072*1024, 3072,
                                                   bih + 3072, gi1, 0);
    {
        const float* whh_l = Whh + (size_t)3072*1024;
        const float* bhh_l = bhh + 3072;
        const float* gi_l  = gi1;
        const float* hi_l  = init_state + HH;
        ushort_t*    ho_l  = h1;
        void* args[] = {(void*)&whh_l, (void*)&bhh_l, (void*)&gi_l, (void*)&hi_l,
                        (void*)&hTa, (void*)&hTb, (void*)&ho_l};
        hipLaunchCooperativeKernel((const void*)k_gru_layer, dim3(256), dim3(256),
                                   args, 0, stream);
    }

    // final projection -> all of d_out (reads only d_ws / d_in)
    if (planA)
        k_gemm_bt<0><<<dim3(79, 65), 256, 0, stream>>>(h1, MM, WoutB, VV, bout, out, 1);
    else
        k_gemm_bt<1><<<dim3(79, 65), 256, 0, stream>>>(h1, MM, Wout,  VV, bout, out, 1);
}

// Round 2
// 7743.117 us; speedup vs baseline: 3.0039x; 3.0039x over previous
//
#include <hip/hip_runtime.h>

typedef unsigned short ushort_t;
typedef unsigned int uint32;

typedef short bf16x8 __attribute__((ext_vector_type(8)));
typedef float f32x4 __attribute__((ext_vector_type(4)));

#define HH 1024
#define BB 32
#define U1 257
#define VV 10001
#define MM (U1*BB)   /* 8224 */
#define KK 1024
#define GRU_WGS 256

__device__ __forceinline__ ushort_t f2bf(float f){
    union { float f; uint32 i; } c; c.f = f;
    uint32 u = c.i;
    uint32 r = (u + 0x7fffu + ((u >> 16) & 1u)) >> 16;  // RNE
    return (ushort_t)r;
}

__global__ __launch_bounds__(256) void k_cast(const float* __restrict__ src,
                                              ushort_t* __restrict__ dst, int n){
    int i = blockIdx.x*256 + threadIdx.x;
    int stride = gridDim.x*256;
    for (; i < n; i += stride) dst[i] = f2bf(src[i]);
}

__global__ __launch_bounds__(64) void k_zero(unsigned int* p, int n){
    int i = threadIdx.x;
    if (i < n) p[i] = 0u;
}

// x0[(t*32+b)*H + k] = bf16(embed[token(t,b)*H + k]); token = start for t=0 else y[b][t-1]
__global__ __launch_bounds__(256) void k_embed(const int* __restrict__ y,
                                               const float* __restrict__ embed,
                                               ushort_t* __restrict__ x0){
    int i = blockIdx.x*256 + threadIdx.x;
    int stride = gridDim.x*256;
    const int n = MM*HH;
    for (; i < n; i += stride){
        int m = i >> 10, k = i & 1023;
        int t = m >> 5, b = m & 31;
        int tok = (t == 0) ? (VV-1) : y[b*256 + (t-1)];
        x0[i] = f2bf(embed[(size_t)tok*HH + k]);
    }
}

// ---------------------------------------------------------------------------
// Persistent GRU layer, custom barrier (no cooperative launch, no L2 fences).
// 256 WGs x 1024 threads, 1 WG/CU (125 KB LDS), 4 waves/SIMD.
// WG wg owns j in [wg*4, wg*4+4). Whh rows staged once to LDS as FP32 (48 KB).
// h exchange: bf16 global buffers written with sc0|sc1 (write-through, device-
// visible at L3), read with sc0|sc1 (L2 bypass), staged per-WG into LDS (64 KB).
// Barrier: per-WG atomicAdd on a counter + sc1 spin, monotonic targets.
// Own h kept FP32 in registers for the z*h blend.
// Thread = (b = tid&31, jl = (tid>>5)&3, kq = tid>>7 in 0..7), 128 k per kq.
// gi layout (mode 2): [t][gate*1024+j][b] fp32 -> coalesced loads over b.
// ---------------------------------------------------------------------------
__global__ __launch_bounds__(1024) void k_gru_layer(
    const float* __restrict__ Whh,   // [3072][1024] fp32 (layer base)
    const float* __restrict__ bhh,   // [3072] (layer base)
    const float* __restrict__ gi,    // [257][3072][32] fp32 (includes bih)
    const float* __restrict__ hinit, // [1024]
    ushort_t* hA, ushort_t* hB,      // bf16 exchange, 32768 each, [k/8][b][8]
    unsigned int* cnt,               // zeroed before launch
    ushort_t* __restrict__ hout)     // [257][32][1024] bf16
{
    __shared__ float    wlds[12*1024];   // 48 KB fp32 weights
    __shared__ ushort_t hlds[32768];     // 64 KB bf16 h
    __shared__ float    part[7][3][128]; // 10.5 KB partials (kq 1..7)

    const int tid = threadIdx.x;
    const int b  = tid & 31;
    const int jl = (tid >> 5) & 3;
    const int kq = tid >> 7;             // 0..7
    const int wg = blockIdx.x;
    const int j  = wg*4 + jl;

    // stage 12 fp32 weight rows (3072 float4s, 3 per thread)
    for (int i = tid; i < 3072; i += 1024){
        int row = i >> 8;                 // 0..11 = g*4+jj
        int e   = (i & 255) << 2;
        int g = row >> 2, jj = row & 3;
        *(float4*)&wlds[row*1024 + e] =
            *(const float4*)(Whh + (size_t)(g*1024 + wg*4 + jj)*1024 + e);
    }

    const int hexid = ((j >> 3) << 8) + (b << 3) + (j & 7);  // ushort index
    float h_own = 0.f, bhr = 0.f, bhz = 0.f, bhn = 0.f;
    if (kq == 0){
        h_own = hinit[j];
        bhr = bhh[j]; bhz = bhh[1024 + j]; bhn = bhh[2048 + j];
        uint32 hb = (uint32)f2bf(h_own);
        asm volatile("global_store_short %0, %1, off sc0 sc1"
                     :: "v"(hA + hexid), "v"(hb) : "memory");
    }
    asm volatile("s_waitcnt vmcnt(0)" ::: "memory");
    __syncthreads();                      // also covers wlds staging
    if (tid == 0){
        atomicAdd(cnt, 1u);
        uint32 v;
        do {
            asm volatile("global_load_dword %0, %1, off sc0 sc1\n\ts_waitcnt vmcnt(0)"
                         : "=v"(v) : "v"(cnt) : "memory");
            if (v >= (uint32)GRU_WGS) break;
            __builtin_amdgcn_s_sleep(1);
        } while (true);
    }
    __syncthreads();

    const float* wr = wlds + (0 + jl)*1024;
    const float* wz = wlds + (4 + jl)*1024;
    const float* wn = wlds + (8 + jl)*1024;
    const ushort_t* hp0 = hlds + kq*4096 + b*8;

    for (int t = 0; t < U1; t++){
        const ushort_t* src = (t & 1) ? hB : hA;
        ushort_t*       dst = (t & 1) ? hA : hB;

        // prefetch gi early (plain cached loads, coalesced over b)
        float gir = 0.f, giz = 0.f, gin = 0.f;
        if (kq == 0){
            const float* g0 = gi + (size_t)t*3072*32 + b;
            gir = g0[(size_t)(0*1024 + j)*32];
            giz = g0[(size_t)(1*1024 + j)*32];
            gin = g0[(size_t)(2*1024 + j)*32];
        }

        // stage 64 KB bf16 h: 4 x dwordx4 per thread, sc1 (L2 bypass)
        uint4 sv[4];
        const char* sp = (const char*)src + tid*16;
        #pragma unroll
        for (int w = 0; w < 4; w++){
            asm volatile("global_load_dwordx4 %0, %1, off sc0 sc1"
                         : "=v"(sv[w]) : "v"(sp + (size_t)w*16384) : "memory");
        }
        asm volatile("s_waitcnt vmcnt(0)" ::: "memory");
        __builtin_amdgcn_sched_barrier(0);
        #pragma unroll
        for (int w = 0; w < 4; w++)
            *(uint4*)&hlds[(size_t)(w*1024 + tid)*8] = sv[w];
        __syncthreads();

        // 128-k partial dots from LDS (fp32 weights x unpacked bf16 h)
        float ar = 0.f, az = 0.f, an = 0.f;
        #pragma unroll 4
        for (int i = 0; i < 16; i++){
            uint4 hv = *(const uint4*)(hp0 + i*256);
            float hf[8];
            const uint32 ha[4] = {hv.x, hv.y, hv.z, hv.w};
            #pragma unroll
            for (int q = 0; q < 4; q++){
                union { uint32 i; float f; } lo, hi;
                lo.i = ha[q] << 16; hi.i = ha[q] & 0xffff0000u;
                hf[2*q] = lo.f; hf[2*q+1] = hi.f;
            }
            int k8 = kq*128 + i*8;
            const float4 r0 = *(const float4*)(wr + k8), r1 = *(const float4*)(wr + k8 + 4);
            const float4 z0 = *(const float4*)(wz + k8), z1 = *(const float4*)(wz + k8 + 4);
            const float4 n0 = *(const float4*)(wn + k8), n1 = *(const float4*)(wn + k8 + 4);
            ar += r0.x*hf[0] + r0.y*hf[1] + r0.z*hf[2] + r0.w*hf[3]
                + r1.x*hf[4] + r1.y*hf[5] + r1.z*hf[6] + r1.w*hf[7];
            az += z0.x*hf[0] + z0.y*hf[1] + z0.z*hf[2] + z0.w*hf[3]
                + z1.x*hf[4] + z1.y*hf[5] + z1.z*hf[6] + z1.w*hf[7];
            an += n0.x*hf[0] + n0.y*hf[1] + n0.z*hf[2] + n0.w*hf[3]
                + n1.x*hf[4] + n1.y*hf[5] + n1.z*hf[6] + n1.w*hf[7];
        }

        if (kq){
            int c = jl*32 + b;
            part[kq-1][0][c] = ar; part[kq-1][1][c] = az; part[kq-1][2][c] = an;
        }
        __syncthreads();
        if (kq == 0){
            int c = jl*32 + b;
            #pragma unroll
            for (int q = 0; q < 7; q++){
                ar += part[q][0][c]; az += part[q][1][c]; an += part[q][2][c];
            }
            float r  = 1.f/(1.f + __expf(-(gir + ar + bhr)));
            float z  = 1.f/(1.f + __expf(-(giz + az + bhz)));
            float nn = tanhf(gin + r*(an + bhn));
            h_own = (1.f - z)*nn + z*h_own;
            ushort_t hb16 = f2bf(h_own);
            __builtin_nontemporal_store(hb16, hout + (size_t)t*(BB*HH) + b*HH + j);
            if (t < U1-1){
                uint32 hb = (uint32)hb16;
                asm volatile("global_store_short %0, %1, off sc0 sc1"
                             :: "v"(dst + hexid), "v"(hb) : "memory");
            }
        }
        if (t < U1-1){
            asm volatile("s_waitcnt vmcnt(0)" ::: "memory");
            __syncthreads();
            if (tid == 0){
                atomicAdd(cnt, 1u);
                uint32 tgt = (uint32)(t + 2)*GRU_WGS;
                uint32 v;
                do {
                    asm volatile("global_load_dword %0, %1, off sc0 sc1\n\ts_waitcnt vmcnt(0)"
                                 : "=v"(v) : "v"(cnt) : "memory");
                    if (v >= tgt) break;
                    __builtin_amdgcn_s_sleep(1);
                } while (true);
            }
            __syncthreads();
        }
    }
}

// C = A @ B^T + bias.  A: [M][1024] bf16. B: [N][1024] row-major, bf16 (BFP32=0)
// or fp32 (BFP32=1). mode 0: C[row*N+col]. mode 1: row=(t*32+b) ->
// C[b*(257*V) + t*V + col]. mode 2: row=(t*32+b) -> C[(t*3072+col)*32 + b].
template<int BFP32>
__global__ __launch_bounds__(256) void k_gemm_bt(
    const ushort_t* __restrict__ A, int M,
    const void* __restrict__ Bv, int N,
    const float* __restrict__ bias,
    float* __restrict__ C, int mode)
{
    int wave = threadIdx.x >> 6;
    int lane = threadIdx.x & 63;
    int quad = lane >> 4;
    int l16  = lane & 15;
    int m0 = blockIdx.y*128 + (wave >> 1)*64;
    int n0 = blockIdx.x*128 + (wave & 1)*64;

    const ushort_t* pA[4];
    const ushort_t* pBh[4];
    const float*    pBf[4];
    #pragma unroll
    for (int i = 0; i < 4; i++){
        int r = m0 + i*16 + l16; if (r > M-1) r = M-1;
        pA[i] = A + (size_t)r*KK + quad*8;
        int c = n0 + i*16 + l16; if (c > N-1) c = N-1;
        if (BFP32) pBf[i] = (const float*)Bv + (size_t)c*KK + quad*8;
        else       pBh[i] = (const ushort_t*)Bv + (size_t)c*KK + quad*8;
    }
    f32x4 acc[4][4];
    #pragma unroll
    for (int i = 0; i < 4; i++)
        #pragma unroll
        for (int j = 0; j < 4; j++){
            f32x4 z4 = {0.f, 0.f, 0.f, 0.f};
            acc[i][j] = z4;
        }

    for (int kc = 0; kc < KK; kc += 32){
        bf16x8 av[4], bv[4];
        #pragma unroll
        for (int i = 0; i < 4; i++) av[i] = *(const bf16x8*)(pA[i] + kc);
        #pragma unroll
        for (int j = 0; j < 4; j++){
            if (BFP32){
                float4 f0 = *(const float4*)(pBf[j] + kc);
                float4 f1 = *(const float4*)(pBf[j] + kc + 4);
                bf16x8 t;
                t[0]=(short)f2bf(f0.x); t[1]=(short)f2bf(f0.y);
                t[2]=(short)f2bf(f0.z); t[3]=(short)f2bf(f0.w);
                t[4]=(short)f2bf(f1.x); t[5]=(short)f2bf(f1.y);
                t[6]=(short)f2bf(f1.z); t[7]=(short)f2bf(f1.w);
                bv[j] = t;
            } else {
                bv[j] = *(const bf16x8*)(pBh[j] + kc);
            }
        }
        #pragma unroll
        for (int i = 0; i < 4; i++)
            #pragma unroll
            for (int j = 0; j < 4; j++)
                acc[i][j] = __builtin_amdgcn_mfma_f32_16x16x32_bf16(av[i], bv[j], acc[i][j], 0, 0, 0);
    }

    #pragma unroll
    for (int i = 0; i < 4; i++){
        int rbase = m0 + i*16 + quad*4;
        #pragma unroll
        for (int j = 0; j < 4; j++){
            int col = n0 + j*16 + l16;
            if (col >= N) continue;
            float bvv = bias[col];
            #pragma unroll
            for (int rr = 0; rr < 4; rr++){
                int row = rbase + rr;
                if (row >= M) continue;
                float v = acc[i][j][rr] + bvv;
                if (mode == 0) C[(size_t)row*N + col] = v;
                else if (mode == 1){
                    int t = row >> 5, b = row & 31;
                    C[(size_t)b*((size_t)U1*VV) + (size_t)t*VV + col] = v;
                } else {
                    int t = row >> 5, b = row & 31;
                    C[((size_t)t*3072 + col)*32 + b] = v;
                }
            }
        }
    }
}

extern "C" void kernel_launch(void* const* d_in, const int* in_sizes, int n_in,
                              void* d_out, int out_size, void* d_ws, size_t ws_size,
                              hipStream_t stream)
{
    const int*   y          = (const int*)  d_in[0];
    const float* embed      = (const float*)d_in[2];
    const float* init_state = (const float*)d_in[3];
    const float* Wih        = (const float*)d_in[4];
    const float* Whh        = (const float*)d_in[5];
    const float* bih        = (const float*)d_in[6];
    const float* bhh        = (const float*)d_in[7];
    const float* Wout       = (const float*)d_in[8];
    const float* bout       = (const float*)d_in[9];
    float* out = (float*)d_out;

    // ---- d_out as scratch (all regions dead before the projection) ----
    float* gi0 = out;                              // 101.1 MB (MM*3072 fp32, mode-2 layout)
    float* gi1 = out + (size_t)MM*3072;            // 101.1 MB
    char*  r2  = (char*)(out + (size_t)2*MM*3072); // spare
    ushort_t* x0   = (ushort_t*)r2;                      // 16.84 MB
    ushort_t* h0   = (ushort_t*)(r2 + (size_t)MM*HH*2);  // 16.84 MB
    ushort_t* WihB = (ushort_t*)(r2 + (size_t)2*MM*HH*2);// 12.58 MB

    // ---- d_ws: buffers that must survive the projection ----
    char* w = (char*)d_ws;
    ushort_t* h1  = (ushort_t*)w; w += (size_t)MM*HH*2;   // 16.84 MB
    ushort_t* hA  = (ushort_t*)w; w += (size_t)32768*2;   // 64 KB bf16 exchange
    ushort_t* hB  = (ushort_t*)w; w += (size_t)32768*2;   // 64 KB
    unsigned int* cnts = (unsigned int*)w; w += 256;      // 2 counters, 64B apart
    size_t used_b = (size_t)(w - (char*)d_ws);
    size_t need_a = used_b + (size_t)VV*1024*2;           // +20.48 MB WoutB
    int planA = (ws_size >= need_a) ? 1 : 0;
    ushort_t* WoutB = (ushort_t*)w;

    k_cast<<<2048, 256, 0, stream>>>(Wih,  WihB,  2*3072*1024);
    if (planA)
        k_cast<<<2048, 256, 0, stream>>>(Wout, WoutB, VV*1024);
    k_embed<<<4096, 256, 0, stream>>>(y, embed, x0);
    unsigned int* cnt0 = cnts;
    unsigned int* cnt1 = cnts + 16;
    k_zero<<<1, 64, 0, stream>>>(cnts, 32);

    // layer 0
    k_gemm_bt<0><<<dim3(24, 65), 256, 0, stream>>>(x0, MM, WihB, 3072, bih, gi0, 2);
    k_gru_layer<<<GRU_WGS, 1024, 0, stream>>>(Whh, bhh, gi0, init_state,
                                              hA, hB, cnt0, h0);

    // layer 1
    k_gemm_bt<0><<<dim3(24, 65), 256, 0, stream>>>(h0, MM, WihB + (size_t)3072*1024, 3072,
                                                   bih + 3072, gi1, 2);
    k_gru_layer<<<GRU_WGS, 1024, 0, stream>>>(Whh + (size_t)3072*1024, bhh + 3072, gi1,
                                              init_state + HH, hA, hB, cnt1, h1);

    // final projection -> all of d_out (reads only d_ws / d_in)
    if (planA)
        k_gemm_bt<0><<<dim3(79, 65), 256, 0, stream>>>(h1, MM, WoutB, VV, bout, out, 1);
    else
        k_gemm_bt<1><<<dim3(79, 65), 256, 0, stream>>>(h1, MM, Wout,  VV, bout, out, 1);
}